// Round 5
// baseline (859.664 us; speedup 1.0000x reference)
//
#include <hip/hip_runtime.h>
#include <stdint.h>

typedef __attribute__((ext_vector_type(8))) short bf16x8;
typedef __attribute__((ext_vector_type(8))) unsigned short u16x8;
typedef __attribute__((ext_vector_type(4))) float f32x4;
typedef __attribute__((ext_vector_type(4))) int i32x4;

static constexpr int MDIM = 8192;   // B*S
static constexpr int KDIM = 4096;   // I
static constexpr int NDIM = 11008;  // O
static constexpr int BM = 256, BN = 256, BK = 64;
static constexpr int NBX = NDIM / BN;  // 43
static constexpr int NBY = MDIM / BM;  // 32

// ---------------- prep: fused A-convert + W-dequant (verified rounds 1-2) ----------------

static __device__ __forceinline__ unsigned short f2bf(float f) {
  unsigned int u = __builtin_bit_cast(unsigned int, f);
  return (unsigned short)((u + 0x7FFFu + ((u >> 16) & 1u)) >> 16);
}

static __device__ __forceinline__ float fp4_val(unsigned int c) {
  unsigned int m = c & 1u, e = (c >> 1) & 3u, s = (c >> 3) & 1u;
  unsigned int bits = e ? (((126u + e) << 23) | (m << 22)) : (m ? 0x3F000000u : 0u);
  bits |= s << 31;
  return __builtin_bit_cast(float, bits);
}

static constexpr int CONV_BLOCKS = (MDIM * KDIM / 8) / 256;     // 16384
static constexpr int DEQ_BLOCKS  = (NDIM * (KDIM / 32)) / 256;  // 5504

__global__ __launch_bounds__(256) void prep_kernel(
    const float4* __restrict__ in, u16x8* __restrict__ aout,
    const int* __restrict__ pw, const int* __restrict__ sc,
    unsigned short* __restrict__ wout) {
  if (blockIdx.x < CONV_BLOCKS) {
    int i = blockIdx.x * 256 + threadIdx.x;
    float4 v0 = in[2 * (size_t)i];
    float4 v1 = in[2 * (size_t)i + 1];
    u16x8 r;
    r[0] = f2bf(v0.x); r[1] = f2bf(v0.y); r[2] = f2bf(v0.z); r[3] = f2bf(v0.w);
    r[4] = f2bf(v1.x); r[5] = f2bf(v1.y); r[6] = f2bf(v1.z); r[7] = f2bf(v1.w);
    aout[i] = r;
  } else {
    int tid = (blockIdx.x - CONV_BLOCKS) * 256 + threadIdx.x;
    int o = tid >> 7;
    int b = tid & 127;
    const i32x4* src = (const i32x4*)(pw + (size_t)o * (KDIM / 2) + b * 16);
    unsigned int e = (unsigned int)sc[(size_t)o * (KDIM / 32) + b];
    float scale = __builtin_bit_cast(float, e << 23);
    unsigned short* dst = wout + (size_t)o * KDIM + b * 32;
#pragma unroll
    for (int v = 0; v < 4; ++v) {
      i32x4 w4 = src[v];
      u16x8 r;
#pragma unroll
      for (int j = 0; j < 4; ++j) {
        unsigned int w = (unsigned int)w4[j];
        r[2 * j]     = f2bf(fp4_val(w & 0xFu) * scale);
        r[2 * j + 1] = f2bf(fp4_val((w >> 4) & 0xFu) * scale);
      }
      *(u16x8*)(dst + 8 * v) = r;
    }
  }
}

// ---------------- GEMM: 256x256, BK=64, 2-slot dbuf, 4 fine phases/K-tile ----------------

#define GLDS16(gp, lp)                                                                  \
  __builtin_amdgcn_global_load_lds((const __attribute__((address_space(1))) void*)(gp), \
                                   (__attribute__((address_space(3))) void*)(lp), 16, 0, 0)

// Barrier that is ALSO a compiler memory fence (rule-#18 class motion hazards).
#define BAR() asm volatile("s_barrier" ::: "memory")

#define MFMA16(ACC, AV, BV, MO)                                                          \
  _Pragma("unroll") for (int m_ = 0; m_ < 4; ++m_)                                       \
  _Pragma("unroll") for (int n_ = 0; n_ < 4; ++n_)                                       \
      ACC[MO + m_][n_] = __builtin_amdgcn_mfma_f32_16x16x32_bf16(AV[m_], BV[n_],         \
                                                                 ACC[MO + m_][n_], 0, 0, 0)

// One K-tile = 4 phases. Stage order across phases: B0,B1 | B2,B3 | A0,A2 | A1,A3.
// Ledger: P1.vmcnt(2) guards {A1,A3}(this tile) for P2 reads; P4.vmcnt(2) guards
// {B0..B3,A0,A2}(next tile) for next P1 reads. Non-stage tile: P1.vmcnt(0), P4 none.
template <int SLOT, bool STAGE>
__device__ __forceinline__ void ktile(
    unsigned char* lds, const unsigned short*& gA, const unsigned short*& gB,
    int stq, int aBase, int bBase, int kof0, int kof1, f32x4 (&acc)[8][4]) {
  const unsigned char* sa = lds + SLOT * 65536;
  const unsigned char* sb = sa + 32768;   // B-half base; bBase is row offset ONLY
  unsigned char* da = lds + (SLOT ^ 1) * 65536 + stq;
  unsigned char* db = da + 32768;
  bf16x8 a[4], b[4], a2[4];

  // ---- P1: mh0 x ks0, B x ks0 ----
#pragma unroll
  for (int m = 0; m < 4; ++m) a[m] = *(const bf16x8*)(sa + aBase + m * 2048 + kof0);
#pragma unroll
  for (int n = 0; n < 4; ++n) b[n] = *(const bf16x8*)(sb + bBase + n * 2048 + kof0);
  if (STAGE) {
    GLDS16(gB, db);
    GLDS16(gB + (size_t)64 * KDIM, db + 8192);
    asm volatile("s_waitcnt vmcnt(2)" ::: "memory");
  } else {
    asm volatile("s_waitcnt vmcnt(0)" ::: "memory");
  }
  BAR();
  __builtin_amdgcn_s_setprio(1);
  MFMA16(acc, a, b, 0);
  __builtin_amdgcn_s_setprio(0);
  BAR();

  // ---- P2: mh1 x ks0 (reuses b) ----
#pragma unroll
  for (int m = 0; m < 4; ++m) a2[m] = *(const bf16x8*)(sa + aBase + (4 + m) * 2048 + kof0);
  if (STAGE) {
    GLDS16(gB + (size_t)128 * KDIM, db + 16384);
    GLDS16(gB + (size_t)192 * KDIM, db + 24576);
  }
  BAR();
  __builtin_amdgcn_s_setprio(1);
  MFMA16(acc, a2, b, 4);
  __builtin_amdgcn_s_setprio(0);
  BAR();

  // ---- P3: mh0 x ks1, B x ks1 ----
#pragma unroll
  for (int m = 0; m < 4; ++m) a[m] = *(const bf16x8*)(sa + aBase + m * 2048 + kof1);
#pragma unroll
  for (int n = 0; n < 4; ++n) b[n] = *(const bf16x8*)(sb + bBase + n * 2048 + kof1);
  if (STAGE) {
    GLDS16(gA, da);
    GLDS16(gA + (size_t)128 * KDIM, da + 16384);
  }
  BAR();
  __builtin_amdgcn_s_setprio(1);
  MFMA16(acc, a, b, 0);
  __builtin_amdgcn_s_setprio(0);
  BAR();

  // ---- P4: mh1 x ks1 ----
#pragma unroll
  for (int m = 0; m < 4; ++m) a2[m] = *(const bf16x8*)(sa + aBase + (4 + m) * 2048 + kof1);
  if (STAGE) {
    GLDS16(gA + (size_t)64 * KDIM, da + 8192);
    GLDS16(gA + (size_t)192 * KDIM, da + 24576);
    gA += BK; gB += BK;
    asm volatile("s_waitcnt vmcnt(2)" ::: "memory");
  }
  BAR();
  __builtin_amdgcn_s_setprio(1);
  MFMA16(acc, a2, b, 4);
  __builtin_amdgcn_s_setprio(0);
  BAR();
}

__global__ __launch_bounds__(512, 2) void gemm_mx_kernel(
    const unsigned short* __restrict__ A,   // [MDIM][KDIM] bf16
    const unsigned short* __restrict__ Bw,  // [NDIM][KDIM] bf16
    const float* __restrict__ bias,
    float* __restrict__ C) {
  __shared__ __align__(16) unsigned char lds[2 * 65536];  // 128 KiB: 2 x (A32K + B32K)

  const int t = threadIdx.x;
  const int lane = t & 63;
  const int wave = t >> 6;
  const int wr = wave >> 2;  // 0..1 (M)
  const int wc = wave & 3;   // 0..3 (N)

  // bijective XCD swizzle (grid 1376 % 8 == 0)
  const int bid = blockIdx.x;
  const int swb = (bid & 7) * ((NBX * NBY) / 8) + (bid >> 3);
  const int by = swb / NBX;
  const int bx = swb - by * NBX;
  const int m0 = by * BM, n0 = bx * BN;

  const int fl = lane & 15;
  const int fh = lane >> 4;
  // read-side swizzle: granule (4*ks + fh) ^ (row & 7), row&7 == fl&7 for all frags
  const int kof0 = ((fh)     ^ (fl & 7)) * 16;
  const int kof1 = ((4 + fh) ^ (fl & 7)) * 16;
  const int aBase = (wr * 128 + fl) * 128;
  const int bBase = (wc * 64 + fl) * 128;   // row offset within B-half (BUGFIX R4->R5:
                                            // was 32768 + ..., double-counting sb's +32768
                                            // -> OOB/cross-slot LDS reads -> NaN)

  // staging: LDS linear; inverse swizzle pre-applied to global source column
  const int stq = t * 16;
  const int srow = t >> 3;                      // row within 64-row load block
  const int koff = 8 * ((t & 7) ^ (srow & 7));  // element offset within row
  const unsigned short* gA = A + (size_t)(m0 + srow) * KDIM + koff;
  const unsigned short* gB = Bw + (size_t)(n0 + srow) * KDIM + koff;

  f32x4 acc[8][4] = {};

  // prologue: tile 0 -> slot 0, canonical order B0,B1,B2,B3,A0,A2,A1,A3
  {
    unsigned char* da = lds + stq;
    unsigned char* db = da + 32768;
    GLDS16(gB, db);
    GLDS16(gB + (size_t)64 * KDIM, db + 8192);
    GLDS16(gB + (size_t)128 * KDIM, db + 16384);
    GLDS16(gB + (size_t)192 * KDIM, db + 24576);
    GLDS16(gA, da);
    GLDS16(gA + (size_t)128 * KDIM, da + 16384);
    GLDS16(gA + (size_t)64 * KDIM, da + 8192);
    GLDS16(gA + (size_t)192 * KDIM, da + 24576);
    gA += BK; gB += BK;
    asm volatile("s_waitcnt vmcnt(2)" ::: "memory");
    BAR();
  }

  // tiles 0..61 (31 x 2), tile 62 (stage 63), tile 63 (drain)
  for (int it = 0; it < 31; ++it) {
    ktile<0, true>(lds, gA, gB, stq, aBase, bBase, kof0, kof1, acc);
    ktile<1, true>(lds, gA, gB, stq, aBase, bBase, kof0, kof1, acc);
  }
  ktile<0, true>(lds, gA, gB, stq, aBase, bBase, kof0, kof1, acc);
  ktile<1, false>(lds, gA, gB, stq, aBase, bBase, kof0, kof1, acc);

  // epilogue: C/D layout col=lane&15, row=(lane>>4)*4+reg  [verified rounds 1-2]
#pragma unroll
  for (int n = 0; n < 4; ++n) {
    const int gn = n0 + wc * 64 + n * 16 + fl;
    const float bv = bias[gn];
#pragma unroll
    for (int m = 0; m < 8; ++m) {
      const int gm = m0 + wr * 128 + m * 16 + fh * 4;
      float* cp = C + (size_t)gm * NDIM + gn;
#pragma unroll
      for (int r = 0; r < 4; ++r)
        cp[(size_t)r * NDIM] = acc[m][n][r] + bv;
    }
  }
}

extern "C" void kernel_launch(void* const* d_in, const int* in_sizes, int n_in,
                              void* d_out, int out_size, void* d_ws, size_t ws_size,
                              hipStream_t stream) {
  const float* inp  = (const float*)d_in[0];
  const float* bias = (const float*)d_in[1];
  const int* pw     = (const int*)d_in[2];
  const int* sc     = (const int*)d_in[3];
  float* out = (float*)d_out;

  unsigned short* a_bf = (unsigned short*)d_ws;
  unsigned short* w_bf = a_bf + (size_t)MDIM * KDIM;
  size_t need = ((size_t)MDIM * KDIM + (size_t)NDIM * KDIM) * sizeof(unsigned short);
  if (ws_size < need) return;

  prep_kernel<<<dim3(CONV_BLOCKS + DEQ_BLOCKS), dim3(256), 0, stream>>>(
      (const float4*)inp, (u16x8*)a_bf, pw, sc, w_bf);
  gemm_mx_kernel<<<dim3(NBX * NBY), dim3(512), 0, stream>>>(a_bf, w_bf, bias, out);
}